// Round 8
// baseline (473.705 us; speedup 1.0000x reference)
//
#include <hip/hip_runtime.h>
#include <hip/hip_bf16.h>
#include <cmath>

#define BQ 2
#define SQ 2048
#define DM 512
#define DI 1024
#define DSTATE 16
#define DCONV 4
#define DTR 32
#define NLAYERS 2
#define CHUNK 64
#define NCH (SQ / CHUNK)   // 32 chunks
#define LOG2E 1.4426950408889634f

typedef __attribute__((ext_vector_type(8))) short bf16x8;
typedef __attribute__((ext_vector_type(4))) float f32x4;

__device__ __forceinline__ unsigned short f2bf(float f) {
    __hip_bfloat16 h = __float2bfloat16(f);
    return *reinterpret_cast<unsigned short*>(&h);
}

// ---------------------------------------------------------------- transpose
__global__ __launch_bounds__(256) void k_transpose(const float* __restrict__ in,
                                                   float* __restrict__ out) {
    __shared__ float tile[32][33];
    int b = blockIdx.z;
    int s0 = blockIdx.x * 32, c0 = blockIdx.y * 32;
    int tx = threadIdx.x, ty = threadIdx.y;  // block (32,8)
#pragma unroll
    for (int i = 0; i < 4; i++)
        tile[ty + i * 8][tx] = in[((size_t)b * DM + c0 + ty + i * 8) * SQ + s0 + tx];
    __syncthreads();
#pragma unroll
    for (int i = 0; i < 4; i++)
        out[((size_t)b * SQ + s0 + ty + i * 8) * DM + c0 + tx] = tile[tx][ty + i * 8];
}

// ---------------------------------------------------------------- fp32 -> bf16 convert
__global__ __launch_bounds__(256) void k_cvt(const float* __restrict__ in,
                                             unsigned short* __restrict__ out, int n4) {
    int i = blockIdx.x * 256 + threadIdx.x;
    if (i >= n4) return;
    float4 v = ((const float4*)in)[i];
    ushort4 o;
    o.x = f2bf(v.x); o.y = f2bf(v.y); o.z = f2bf(v.z); o.w = f2bf(v.w);
    ((ushort4*)out)[i] = o;
}

// ---------------------------------------------------------------- rmsnorm bf16 out
__global__ __launch_bounds__(256) void k_rmsnorm_bf(const float* __restrict__ x,
                                                    const float* __restrict__ w,
                                                    unsigned short* __restrict__ out) {
    int row = blockIdx.x;
    const float* xr = x + (size_t)row * DM;
    float v0 = xr[threadIdx.x];
    float v1 = xr[threadIdx.x + 256];
    float ss = v0 * v0 + v1 * v1;
#pragma unroll
    for (int off = 32; off >= 1; off >>= 1) ss += __shfl_xor(ss, off);
    __shared__ float wc[4];
    if ((threadIdx.x & 63) == 0) wc[threadIdx.x >> 6] = ss;
    __syncthreads();
    ss = wc[0] + wc[1] + wc[2] + wc[3];
    float r = rsqrtf(ss * (1.0f / DM) + 1e-5f);
    out[(size_t)row * DM + threadIdx.x] = f2bf(v0 * r * w[threadIdx.x]);
    out[(size_t)row * DM + threadIdx.x + 256] = f2bf(v1 * r * w[threadIdx.x + 256]);
}

// ---------------------------------------------------------------- rmsnorm fp32 out
__global__ __launch_bounds__(256) void k_rmsnorm_f32(const float* __restrict__ x,
                                                     const float* __restrict__ w,
                                                     float* __restrict__ out) {
    int row = blockIdx.x;
    const float* xr = x + (size_t)row * DM;
    float v0 = xr[threadIdx.x];
    float v1 = xr[threadIdx.x + 256];
    float ss = v0 * v0 + v1 * v1;
#pragma unroll
    for (int off = 32; off >= 1; off >>= 1) ss += __shfl_xor(ss, off);
    __shared__ float wc[4];
    if ((threadIdx.x & 63) == 0) wc[threadIdx.x >> 6] = ss;
    __syncthreads();
    ss = wc[0] + wc[1] + wc[2] + wc[3];
    float r = rsqrtf(ss * (1.0f / DM) + 1e-5f);
    out[(size_t)row * DM + threadIdx.x] = v0 * r * w[threadIdx.x];
    out[(size_t)row * DM + threadIdx.x + 256] = v1 * r * w[threadIdx.x + 256];
}

// ---------------------------------------------------------------- templated bf16 MFMA GEMM
// C = A @ W^T (+bias, +act, +resid). A (M,K) bf16, W (N,K) bf16, C f32.
// 4 waves arranged 2x2; wave tile = (BM/2) x (BN/2). AFR=BM/32, BFR=BN/32.
template<int BM, int BN, int AFR, int BFR>
__global__ __launch_bounds__(256) void k_gemm_bf16_t(const unsigned short* __restrict__ A, int lda,
                                                     const unsigned short* __restrict__ W, int ldw,
                                                     float* __restrict__ C, int ldc, int K,
                                                     const float* __restrict__ bias, int act,
                                                     const float* __restrict__ resid, int ldr) {
    __shared__ __align__(16) unsigned short As[BM * 32];
    __shared__ __align__(16) unsigned short Bs[BN * 32];
    const int bm = blockIdx.y * BM, bn = blockIdx.x * BN;
    const int tid = threadIdx.x;
    const int w = tid >> 6, l = tid & 63;
    const int wr = w >> 1, wc = w & 1;
    const int lg = l >> 4, lr16 = l & 15;
    f32x4 acc[AFR][BFR] = {};
    for (int k0 = 0; k0 < K; k0 += 32) {
        __syncthreads();
#pragma unroll
        for (int i = 0; i < BM / 64; i++) {
            int slot = i * 256 + tid;
            int row = slot >> 2, s = slot & 3;
            int sg = s ^ (row & 3);
            __builtin_amdgcn_global_load_lds(
                (const __attribute__((address_space(1))) unsigned int*)(A + (size_t)(bm + row) * lda + k0 + sg * 8),
                (__attribute__((address_space(3))) unsigned int*)(As + slot * 8), 16, 0, 0);
        }
#pragma unroll
        for (int i = 0; i < BN / 64; i++) {
            int slot = i * 256 + tid;
            int row = slot >> 2, s = slot & 3;
            int sg = s ^ (row & 3);
            __builtin_amdgcn_global_load_lds(
                (const __attribute__((address_space(1))) unsigned int*)(W + (size_t)(bn + row) * ldw + k0 + sg * 8),
                (__attribute__((address_space(3))) unsigned int*)(Bs + slot * 8), 16, 0, 0);
        }
        asm volatile("s_waitcnt vmcnt(0)" ::: "memory");
        __syncthreads();
        bf16x8 fa[AFR], fb[BFR];
#pragma unroll
        for (int f = 0; f < AFR; f++) {
            int ar = wr * (BM / 2) + f * 16 + lr16;
            fa[f] = *(const bf16x8*)&As[ar * 32 + (lg ^ (ar & 3)) * 8];
        }
#pragma unroll
        for (int f = 0; f < BFR; f++) {
            int br = wc * (BN / 2) + f * 16 + lr16;
            fb[f] = *(const bf16x8*)&Bs[br * 32 + (lg ^ (br & 3)) * 8];
        }
#pragma unroll
        for (int fi = 0; fi < AFR; fi++)
#pragma unroll
            for (int fj = 0; fj < BFR; fj++)
                acc[fi][fj] = __builtin_amdgcn_mfma_f32_16x16x32_bf16(fa[fi], fb[fj], acc[fi][fj], 0, 0, 0);
    }
#pragma unroll
    for (int fi = 0; fi < AFR; fi++)
#pragma unroll
        for (int fj = 0; fj < BFR; fj++)
#pragma unroll
            for (int r = 0; r < 4; r++) {
                int m = bm + wr * (BM / 2) + fi * 16 + lg * 4 + r;
                int n = bn + wc * (BN / 2) + fj * 16 + lr16;
                float v = acc[fi][fj][r];
                if (bias) v += bias[n];
                if (act == 1) v = fmaxf(v, 0.f) + log1pf(expf(-fabsf(v)));
                if (resid) v += resid[(size_t)m * ldr + n];
                C[(size_t)m * ldc + n] = v;
            }
}

// ---------------------------------------------------------------- x_proj split-K (N=64)
// grid (M/128, 8): K-slab of 128 per blockIdx.y; partial f32 output per slab.
__global__ __launch_bounds__(256) void k_gemm_n64_sk(const unsigned short* __restrict__ A, int lda,
                                                     const unsigned short* __restrict__ W, int ldw,
                                                     float* __restrict__ part) {
    __shared__ __align__(16) unsigned short As[128 * 32];
    __shared__ __align__(16) unsigned short Bs[64 * 32];
    const int bm = blockIdx.x * 128;
    const int koff = blockIdx.y * 128;
    const int tid = threadIdx.x;
    const int w = tid >> 6, l = tid & 63;
    const int lg = l >> 4, lr16 = l & 15;
    f32x4 acc[2][4] = {};
    for (int k0 = koff; k0 < koff + 128; k0 += 32) {
        __syncthreads();
#pragma unroll
        for (int i = 0; i < 2; i++) {
            int slot = i * 256 + tid;
            int row = slot >> 2, s = slot & 3;
            int sg = s ^ (row & 3);
            __builtin_amdgcn_global_load_lds(
                (const __attribute__((address_space(1))) unsigned int*)(A + (size_t)(bm + row) * lda + k0 + sg * 8),
                (__attribute__((address_space(3))) unsigned int*)(As + slot * 8), 16, 0, 0);
        }
        {
            int slot = tid;
            int row = slot >> 2, s = slot & 3;
            int sg = s ^ (row & 3);
            __builtin_amdgcn_global_load_lds(
                (const __attribute__((address_space(1))) unsigned int*)(W + (size_t)row * ldw + k0 + sg * 8),
                (__attribute__((address_space(3))) unsigned int*)(Bs + slot * 8), 16, 0, 0);
        }
        asm volatile("s_waitcnt vmcnt(0)" ::: "memory");
        __syncthreads();
        bf16x8 fa[2], fb[4];
#pragma unroll
        for (int f = 0; f < 2; f++) {
            int ar = w * 32 + f * 16 + lr16;
            fa[f] = *(const bf16x8*)&As[ar * 32 + (lg ^ (ar & 3)) * 8];
        }
#pragma unroll
        for (int f = 0; f < 4; f++) {
            int br = f * 16 + lr16;
            fb[f] = *(const bf16x8*)&Bs[br * 32 + (lg ^ (br & 3)) * 8];
        }
#pragma unroll
        for (int fi = 0; fi < 2; fi++)
#pragma unroll
            for (int fj = 0; fj < 4; fj++)
                acc[fi][fj] = __builtin_amdgcn_mfma_f32_16x16x32_bf16(fa[fi], fb[fj], acc[fi][fj], 0, 0, 0);
    }
    float* out = part + (size_t)blockIdx.y * ((size_t)BQ * SQ * 64);
#pragma unroll
    for (int fi = 0; fi < 2; fi++)
#pragma unroll
        for (int fj = 0; fj < 4; fj++)
#pragma unroll
            for (int r = 0; r < 4; r++) {
                int m = bm + w * 32 + fi * 16 + lg * 4 + r;
                int n = fj * 16 + lr16;
                out[(size_t)m * 64 + n] = acc[fi][fj][r];
            }
}

// ---------------------------------------------------------------- xdbl reduce (8 K-slabs) -> f32 + bf16
__global__ __launch_bounds__(256) void k_xdbl_reduce(const float* __restrict__ part,
                                                     float* __restrict__ xdbl,
                                                     unsigned short* __restrict__ xbf) {
    const int n4 = BQ * SQ * 64 / 4;   // 65536
    int i = blockIdx.x * 256 + threadIdx.x;
    if (i >= n4) return;
    float4 s = ((const float4*)part)[i];
#pragma unroll
    for (int ks = 1; ks < 8; ks++) {
        float4 t = ((const float4*)part)[(size_t)ks * n4 + i];
        s.x += t.x; s.y += t.y; s.z += t.z; s.w += t.w;
    }
    ((float4*)xdbl)[i] = s;
    ushort4 o;
    o.x = f2bf(s.x); o.y = f2bf(s.y); o.z = f2bf(s.z); o.w = f2bf(s.w);
    ((ushort4*)xbf)[i] = o;
}

// ---------------------------------------------------------------- causal conv (k=4) + silu, sliding window
// thread owns one d over 64 t; grid (SQ/64, DI/256, BQ)
__global__ __launch_bounds__(256) void k_conv_silu(const float* __restrict__ xz,
                                                   const float* __restrict__ cw,
                                                   const float* __restrict__ cb,
                                                   float* __restrict__ u,
                                                   unsigned short* __restrict__ ubf) {
    int b = blockIdx.z;
    int t0 = blockIdx.x * 64;
    int d = blockIdx.y * 256 + threadIdx.x;
    float4 wv = ((const float4*)cw)[d];
    float bias = cb[d];
    const size_t rs = 2 * DI;
    size_t base = (size_t)b * SQ * rs + d;
    float x0 = 0.f, x1 = 0.f, x2 = 0.f;
    if (t0 > 0) {
        x0 = xz[base + (size_t)(t0 - 3) * rs];
        x1 = xz[base + (size_t)(t0 - 2) * rs];
        x2 = xz[base + (size_t)(t0 - 1) * rs];
    }
    for (int t = t0; t < t0 + 64; t++) {
        float x3 = xz[base + (size_t)t * rs];
        float a = bias + wv.x * x0 + wv.y * x1 + wv.z * x2 + wv.w * x3;
        float sig = 1.f / (1.f + __expf(-a));
        float v = a * sig;
        size_t o = (size_t)(b * SQ + t) * DI + d;
        u[o] = v;
        ubf[o] = f2bf(v);
        x0 = x1; x1 = x2; x2 = x3;
    }
}

// ---------------------------------------------------------------- chunked scan, phase 1
// 4 states/lane; block 256 = 4q x 64dl; grid = B * NCH * (DI/64)
__global__ __launch_bounds__(256) void k_scan_p1(const float* __restrict__ xdbl,
                                                 const float* __restrict__ dt,
                                                 const float* __restrict__ u,
                                                 const float* __restrict__ A_log,
                                                 float* __restrict__ hend,
                                                 float* __restrict__ dchunk) {
    int bc = blockIdx.x >> 4;          // b*NCH + c
    int d0 = (blockIdx.x & 15) << 6;
    int b = bc >> 5;                   // NCH == 32
    int c = bc & (NCH - 1);
    int tid = threadIdx.x;
    int q = tid & 3, dl = tid >> 2;
    int d = d0 + dl;
    float4 av = *(const float4*)&A_log[((size_t)d << 4) + 4 * q];
    float a0 = -expf(av.x) * LOG2E, a1 = -expf(av.y) * LOG2E;
    float a2 = -expf(av.z) * LOG2E, a3 = -expf(av.w) * LOG2E;
    float h0 = 0.f, h1 = 0.f, h2 = 0.f, h3 = 0.f, sumdt = 0.f;
    __shared__ __align__(16) float sdt[32][68], su[32][68];
    __shared__ __align__(16) float sB[32][20];
    int tbase = c * CHUNK;
    for (int t0 = 0; t0 < CHUNK; t0 += 32) {
        __syncthreads();
#pragma unroll
        for (int i = 0; i < 2; i++) {
            int e = i * 256 + tid;
            int tt = e >> 4, j4 = e & 15;
            size_t rowm = (size_t)(b * SQ + tbase + t0 + tt);
            *(float4*)&sdt[tt][j4 * 4] = *(const float4*)&dt[rowm * DI + d0 + j4 * 4];
            *(float4*)&su[tt][j4 * 4]  = *(const float4*)&u[rowm * DI + d0 + j4 * 4];
        }
        if (tid < 128) {
            int tt = tid >> 2, j4 = tid & 3;
            size_t rowm = (size_t)(b * SQ + tbase + t0 + tt);
            *(float4*)&sB[tt][j4 * 4] = *(const float4*)&xdbl[rowm * 64 + DTR + j4 * 4];
        }
        __syncthreads();
        for (int tt = 0; tt < 32; tt++) {
            float dtv = sdt[tt][dl], uv = su[tt][dl];
            float dtu = dtv * uv;
            sumdt += dtv;
            float4 Bv = *(const float4*)&sB[tt][4 * q];
            h0 = exp2f(dtv * a0) * h0 + dtu * Bv.x;
            h1 = exp2f(dtv * a1) * h1 + dtu * Bv.y;
            h2 = exp2f(dtv * a2) * h2 + dtu * Bv.z;
            h3 = exp2f(dtv * a3) * h3 + dtu * Bv.w;
        }
    }
    size_t o = ((size_t)bc << 14) + ((size_t)d << 4) + 4 * q;
    *(float4*)&hend[o] = make_float4(h0, h1, h2, h3);
    *(float4*)&dchunk[o] = make_float4(exp2f(a0 * sumdt), exp2f(a1 * sumdt),
                                       exp2f(a2 * sumdt), exp2f(a3 * sumdt));
}

// ---------------------------------------------------------------- chunked scan, phase 2
__global__ __launch_bounds__(256) void k_scan_p2(const float* __restrict__ hend,
                                                 const float* __restrict__ dchunk,
                                                 float* __restrict__ hstart) {
    int tid = blockIdx.x * 256 + threadIdx.x;
    int b = tid >> 14;
    int ds = tid & 16383;
    float h = 0.f;
#pragma unroll
    for (int c = 0; c < NCH; c++) {
        size_t o = (((size_t)(b * NCH + c)) << 14) + ds;
        hstart[o] = h;
        h = dchunk[o] * h + hend[o];
    }
}

// ---------------------------------------------------------------- chunked scan, phase 3
__global__ __launch_bounds__(256) void k_scan_p3(const float* __restrict__ xdbl,
                                                 const float* __restrict__ dt,
                                                 const float* __restrict__ u,
                                                 const float* __restrict__ xz,
                                                 const float* __restrict__ A_log,
                                                 const float* __restrict__ Dp,
                                                 const float* __restrict__ hstart,
                                                 unsigned short* __restrict__ yout) {
    int bc = blockIdx.x >> 4;
    int d0 = (blockIdx.x & 15) << 6;
    int b = bc >> 5;
    int c = bc & (NCH - 1);
    int tid = threadIdx.x;
    int q = tid & 3, dl = tid >> 2;
    int d = d0 + dl;
    float4 av = *(const float4*)&A_log[((size_t)d << 4) + 4 * q];
    float a0 = -expf(av.x) * LOG2E, a1 = -expf(av.y) * LOG2E;
    float a2 = -expf(av.z) * LOG2E, a3 = -expf(av.w) * LOG2E;
    size_t o = ((size_t)bc << 14) + ((size_t)d << 4) + 4 * q;
    float4 hv = *(const float4*)&hstart[o];
    float h0 = hv.x, h1 = hv.y, h2 = hv.z, h3 = hv.w;
    float Dv = Dp[d];
    __shared__ __align__(16) float sdt[32][68], su[32][68], sz[32][68];
    __shared__ __align__(16) float sBC[32][36];
    int tbase = c * CHUNK;
    for (int t0 = 0; t0 < CHUNK; t0 += 32) {
        __syncthreads();
#pragma unroll
        for (int i = 0; i < 2; i++) {
            int e = i * 256 + tid;
            int tt = e >> 4, j4 = e & 15;
            size_t rowm = (size_t)(b * SQ + tbase + t0 + tt);
            *(float4*)&sdt[tt][j4 * 4] = *(const float4*)&dt[rowm * DI + d0 + j4 * 4];
            *(float4*)&su[tt][j4 * 4]  = *(const float4*)&u[rowm * DI + d0 + j4 * 4];
            *(float4*)&sz[tt][j4 * 4]  = *(const float4*)&xz[rowm * (2 * DI) + DI + d0 + j4 * 4];
        }
        {
            int tt = tid >> 3, j4 = tid & 7;
            size_t rowm = (size_t)(b * SQ + tbase + t0 + tt);
            *(float4*)&sBC[tt][j4 * 4] = *(const float4*)&xdbl[rowm * 64 + DTR + j4 * 4];
        }
        __syncthreads();
        for (int tt = 0; tt < 32; tt++) {
            float dtv = sdt[tt][dl], uv = su[tt][dl];
            float dtu = dtv * uv;
            float4 Bv = *(const float4*)&sBC[tt][4 * q];
            float4 Cv = *(const float4*)&sBC[tt][16 + 4 * q];
            h0 = exp2f(dtv * a0) * h0 + dtu * Bv.x;
            h1 = exp2f(dtv * a1) * h1 + dtu * Bv.y;
            h2 = exp2f(dtv * a2) * h2 + dtu * Bv.z;
            h3 = exp2f(dtv * a3) * h3 + dtu * Bv.w;
            float y = h0 * Cv.x + h1 * Cv.y + h2 * Cv.z + h3 * Cv.w;
            y += __shfl_xor(y, 1);
            y += __shfl_xor(y, 2);
            if (q == 0) {
                y += uv * Dv;
                float zv = sz[tt][dl];
                float g = zv / (1.f + __expf(-zv));
                yout[(size_t)(b * SQ + tbase + t0 + tt) * DI + d] = f2bf(y * g);
            }
        }
    }
}

// ---------------------------------------------------------------- emb gather (mask int32)
__global__ __launch_bounds__(256) void k_emb(const float* __restrict__ tokens,
                                             const int* __restrict__ mask,
                                             float* __restrict__ emb) {
    int b = blockIdx.x;
    int cnt = 0;
    for (int i = threadIdx.x; i < SQ; i += 256) cnt += mask[b * SQ + i] ? 1 : 0;
#pragma unroll
    for (int off = 32; off >= 1; off >>= 1) cnt += __shfl_xor(cnt, off);
    __shared__ int wc[4];
    if ((threadIdx.x & 63) == 0) wc[threadIdx.x >> 6] = cnt;
    __syncthreads();
    int total = wc[0] + wc[1] + wc[2] + wc[3];
    int idx = total > 0 ? total - 1 : 0;
    for (int i = threadIdx.x; i < DM; i += 256)
        emb[b * DM + i] = tokens[((size_t)b * SQ + idx) * DM + i];
}

// ---------------------------------------------------------------- host
extern "C" void kernel_launch(void* const* d_in, const int* in_sizes, int n_in,
                              void* d_out, int out_size, void* d_ws, size_t ws_size,
                              hipStream_t stream) {
    const float* input_data   = (const float*)d_in[0];
    const int*   mask         = (const int*)d_in[1];
    const float* in_proj_w    = (const float*)d_in[2];
    const float* conv_w       = (const float*)d_in[3];
    const float* conv_b       = (const float*)d_in[4];
    const float* xproj_w      = (const float*)d_in[5];
    const float* dtproj_w     = (const float*)d_in[6];
    const float* dtproj_b     = (const float*)d_in[7];
    const float* A_log        = (const float*)d_in[8];
    const float* Dp           = (const float*)d_in[9];
    const float* outproj_w    = (const float*)d_in[10];
    const float* norm_w       = (const float*)d_in[11];
    const float* final_norm_w = (const float*)d_in[12];
    float* out = (float*)d_out;

    const size_t M = (size_t)BQ * SQ;                  // 4096
    const size_t CS = (size_t)BQ * NCH * DI * DSTATE;  // 1,048,576
    float* x              = (float*)d_ws;                       // M*DM f32
    unsigned short* xn_bf = (unsigned short*)(x + M * DM);      // M*DM bf16
    float* xz             = (float*)(xn_bf + M * DM);           // M*2DI f32
    float* u              = xz + M * 2 * DI;                    // M*DI f32
    float* xdbl           = u + M * DI;                         // M*64 f32
    float* dtb            = xdbl + M * 64;                      // M*DI f32
    unsigned short* ubf   = (unsigned short*)(dtb + M * DI);    // M*DI bf16
    unsigned short* ybf   = ubf + M * DI;                       // M*DI bf16
    float* hend           = (float*)(ybf + M * DI);             // CS
    float* dchunk         = hend + CS;                          // CS
    float* hstart         = dchunk + CS;                        // CS
    float* xpart          = hstart + CS;                        // 8*M*64 f32
    unsigned short* xdbl_bf = (unsigned short*)(xpart + 8 * M * 64); // M*64 bf16
    unsigned short* wbf_in  = xdbl_bf + M * 64;                 // L*2DI*DM
    unsigned short* wbf_out = wbf_in + (size_t)NLAYERS * 2 * DI * DM;  // L*DM*DI
    unsigned short* wbf_x   = wbf_out + (size_t)NLAYERS * DM * DI;     // L*64*DI
    unsigned short* wbf_dt  = wbf_x + (size_t)NLAYERS * 64 * DI;       // L*DI*DTR

    // weight conversions
    {
        int n4 = NLAYERS * 2 * DI * DM / 4;
        k_cvt<<<(n4 + 255) / 256, 256, 0, stream>>>(in_proj_w, wbf_in, n4);
        n4 = NLAYERS * DM * DI / 4;
        k_cvt<<<(n4 + 255) / 256, 256, 0, stream>>>(outproj_w, wbf_out, n4);
        n4 = NLAYERS * 64 * DI / 4;
        k_cvt<<<(n4 + 255) / 256, 256, 0, stream>>>(xproj_w, wbf_x, n4);
        n4 = NLAYERS * DI * DTR / 4;
        k_cvt<<<(n4 + 255) / 256, 256, 0, stream>>>(dtproj_w, wbf_dt, n4);
    }

    // x = transpose(input_data)
    k_transpose<<<dim3(SQ / 32, DM / 32, BQ), dim3(32, 8), 0, stream>>>(input_data, x);

    for (int l = 0; l < NLAYERS; l++) {
        // xn_bf = bf16(rmsnorm(x))
        k_rmsnorm_bf<<<M, 256, 0, stream>>>(x, norm_w + (size_t)l * DM, xn_bf);
        // xz = xn @ in_proj^T   (M x 2048, K=512)
        k_gemm_bf16_t<128, 128, 4, 4><<<dim3(2 * DI / 128, M / 128), 256, 0, stream>>>(
            xn_bf, DM, wbf_in + (size_t)l * 2 * DI * DM, DM, xz, 2 * DI, DM,
            nullptr, 0, nullptr, 0);
        // u = silu(conv(xz[:, :DI]))
        k_conv_silu<<<dim3(SQ / 64, DI / 256, BQ), 256, 0, stream>>>(
            xz, conv_w + (size_t)l * DI * DCONV, conv_b + (size_t)l * DI, u, ubf);
        // xdbl = u @ xproj^T   (split-K 8 + reduce; also emits bf16 xdbl)
        k_gemm_n64_sk<<<dim3(M / 128, 8), 256, 0, stream>>>(
            ubf, DI, wbf_x + (size_t)l * 64 * DI, DI, xpart);
        k_xdbl_reduce<<<(BQ * SQ * 64 / 4 + 255) / 256, 256, 0, stream>>>(
            xpart, xdbl, xdbl_bf);
        // dt = softplus(xdbl[:, :32] @ dtproj^T + b)   [bf16 MFMA, K=32]
        k_gemm_bf16_t<64, 128, 2, 4><<<dim3(DI / 128, M / 64), 256, 0, stream>>>(
            xdbl_bf, 64, wbf_dt + (size_t)l * DI * DTR, DTR, dtb, DI, DTR,
            dtproj_b + (size_t)l * DI, 1, nullptr, 0);
        // chunked scan
        k_scan_p1<<<BQ * NCH * (DI / 64), 256, 0, stream>>>(
            xdbl, dtb, u, A_log + (size_t)l * DI * DSTATE, hend, dchunk);
        k_scan_p2<<<(BQ * DI * DSTATE) / 256, 256, 0, stream>>>(hend, dchunk, hstart);
        k_scan_p3<<<BQ * NCH * (DI / 64), 256, 0, stream>>>(
            xdbl, dtb, u, xz, A_log + (size_t)l * DI * DSTATE, Dp + (size_t)l * DI,
            hstart, ybf);
        // x = x + ybf @ outproj^T   (M x 512, K=1024), BM=64 for 256 blocks
        k_gemm_bf16_t<64, 128, 2, 4><<<dim3(DM / 128, M / 64), 256, 0, stream>>>(
            ybf, DI, wbf_out + (size_t)l * DM * DI, DI, x, DM, DI,
            nullptr, 0, x, DM);
    }

    // tokens = rmsnorm(x, final_norm_w)
    k_rmsnorm_f32<<<M, 256, 0, stream>>>(x, final_norm_w, out);
    // emb
    k_emb<<<BQ, 256, 0, stream>>>(out, mask, out + M * DM);
}

// Round 11
// 469.009 us; speedup vs baseline: 1.0100x; 1.0100x over previous
//
#include <hip/hip_runtime.h>
#include <hip/hip_bf16.h>
#include <cmath>

#define BQ 2
#define SQ 2048
#define DM 512
#define DI 1024
#define DSTATE 16
#define DCONV 4
#define DTR 32
#define NLAYERS 2
#define CHUNK 32
#define NCH (SQ / CHUNK)   // 64 chunks
#define LOG2E 1.4426950408889634f

typedef __attribute__((ext_vector_type(8))) short bf16x8;
typedef __attribute__((ext_vector_type(4))) float f32x4;

__device__ __forceinline__ unsigned short f2bf(float f) {
    __hip_bfloat16 h = __float2bfloat16(f);
    return *reinterpret_cast<unsigned short*>(&h);
}

// ---------------------------------------------------------------- transpose
__global__ __launch_bounds__(256) void k_transpose(const float* __restrict__ in,
                                                   float* __restrict__ out) {
    __shared__ float tile[32][33];
    int b = blockIdx.z;
    int s0 = blockIdx.x * 32, c0 = blockIdx.y * 32;
    int tx = threadIdx.x, ty = threadIdx.y;  // block (32,8)
#pragma unroll
    for (int i = 0; i < 4; i++)
        tile[ty + i * 8][tx] = in[((size_t)b * DM + c0 + ty + i * 8) * SQ + s0 + tx];
    __syncthreads();
#pragma unroll
    for (int i = 0; i < 4; i++)
        out[((size_t)b * SQ + s0 + ty + i * 8) * DM + c0 + tx] = tile[tx][ty + i * 8];
}

// ---------------------------------------------------------------- fused fp32->bf16 weight convert
// seg0 in_proj, seg1 outproj, seg2 xproj, seg3 dtproj (element counts /4)
#define N4_IN  (NLAYERS * 2 * DI * DM / 4)   // 524288
#define N4_OUT (NLAYERS * DM * DI / 4)       // 262144
#define N4_X   (NLAYERS * 64 * DI / 4)       // 32768
#define N4_DT  (NLAYERS * DI * DTR / 4)      // 16384
#define N4_ALL (N4_IN + N4_OUT + N4_X + N4_DT)

__global__ __launch_bounds__(256) void k_cvt_all(const float* __restrict__ s0,
                                                 const float* __restrict__ s1,
                                                 const float* __restrict__ s2,
                                                 const float* __restrict__ s3,
                                                 unsigned short* __restrict__ d0,
                                                 unsigned short* __restrict__ d1,
                                                 unsigned short* __restrict__ d2,
                                                 unsigned short* __restrict__ d3) {
    int i = blockIdx.x * 256 + threadIdx.x;
    if (i >= N4_ALL) return;
    const float* src; unsigned short* dst; int j = i;
    if (j < N4_IN) { src = s0; dst = d0; }
    else if ((j -= N4_IN) < N4_OUT) { src = s1; dst = d1; }
    else if ((j -= N4_OUT) < N4_X) { src = s2; dst = d2; }
    else { j -= N4_X; src = s3; dst = d3; }
    float4 v = ((const float4*)src)[j];
    ushort4 o;
    o.x = f2bf(v.x); o.y = f2bf(v.y); o.z = f2bf(v.z); o.w = f2bf(v.w);
    ((ushort4*)dst)[j] = o;
}

// ---------------------------------------------------------------- rmsnorm bf16 out
__global__ __launch_bounds__(256) void k_rmsnorm_bf(const float* __restrict__ x,
                                                    const float* __restrict__ w,
                                                    unsigned short* __restrict__ out) {
    int row = blockIdx.x;
    const float* xr = x + (size_t)row * DM;
    float v0 = xr[threadIdx.x];
    float v1 = xr[threadIdx.x + 256];
    float ss = v0 * v0 + v1 * v1;
#pragma unroll
    for (int off = 32; off >= 1; off >>= 1) ss += __shfl_xor(ss, off);
    __shared__ float wc[4];
    if ((threadIdx.x & 63) == 0) wc[threadIdx.x >> 6] = ss;
    __syncthreads();
    ss = wc[0] + wc[1] + wc[2] + wc[3];
    float r = rsqrtf(ss * (1.0f / DM) + 1e-5f);
    out[(size_t)row * DM + threadIdx.x] = f2bf(v0 * r * w[threadIdx.x]);
    out[(size_t)row * DM + threadIdx.x + 256] = f2bf(v1 * r * w[threadIdx.x + 256]);
}

// ---------------------------------------------------------------- rmsnorm fp32 out
__global__ __launch_bounds__(256) void k_rmsnorm_f32(const float* __restrict__ x,
                                                     const float* __restrict__ w,
                                                     float* __restrict__ out) {
    int row = blockIdx.x;
    const float* xr = x + (size_t)row * DM;
    float v0 = xr[threadIdx.x];
    float v1 = xr[threadIdx.x + 256];
    float ss = v0 * v0 + v1 * v1;
#pragma unroll
    for (int off = 32; off >= 1; off >>= 1) ss += __shfl_xor(ss, off);
    __shared__ float wc[4];
    if ((threadIdx.x & 63) == 0) wc[threadIdx.x >> 6] = ss;
    __syncthreads();
    ss = wc[0] + wc[1] + wc[2] + wc[3];
    float r = rsqrtf(ss * (1.0f / DM) + 1e-5f);
    out[(size_t)row * DM + threadIdx.x] = v0 * r * w[threadIdx.x];
    out[(size_t)row * DM + threadIdx.x + 256] = v1 * r * w[threadIdx.x + 256];
}

// ---------------------------------------------------------------- templated bf16 MFMA GEMM
template<int BM, int BN, int AFR, int BFR>
__global__ __launch_bounds__(256) void k_gemm_bf16_t(const unsigned short* __restrict__ A, int lda,
                                                     const unsigned short* __restrict__ W, int ldw,
                                                     float* __restrict__ C, int ldc, int K,
                                                     const float* __restrict__ bias, int act,
                                                     const float* __restrict__ resid, int ldr) {
    __shared__ __align__(16) unsigned short As[BM * 32];
    __shared__ __align__(16) unsigned short Bs[BN * 32];
    const int bm = blockIdx.y * BM, bn = blockIdx.x * BN;
    const int tid = threadIdx.x;
    const int w = tid >> 6, l = tid & 63;
    const int wr = w >> 1, wc = w & 1;
    const int lg = l >> 4, lr16 = l & 15;
    f32x4 acc[AFR][BFR] = {};
    for (int k0 = 0; k0 < K; k0 += 32) {
        __syncthreads();
#pragma unroll
        for (int i = 0; i < BM / 64; i++) {
            int slot = i * 256 + tid;
            int row = slot >> 2, s = slot & 3;
            int sg = s ^ (row & 3);
            __builtin_amdgcn_global_load_lds(
                (const __attribute__((address_space(1))) unsigned int*)(A + (size_t)(bm + row) * lda + k0 + sg * 8),
                (__attribute__((address_space(3))) unsigned int*)(As + slot * 8), 16, 0, 0);
        }
#pragma unroll
        for (int i = 0; i < BN / 64; i++) {
            int slot = i * 256 + tid;
            int row = slot >> 2, s = slot & 3;
            int sg = s ^ (row & 3);
            __builtin_amdgcn_global_load_lds(
                (const __attribute__((address_space(1))) unsigned int*)(W + (size_t)(bn + row) * ldw + k0 + sg * 8),
                (__attribute__((address_space(3))) unsigned int*)(Bs + slot * 8), 16, 0, 0);
        }
        asm volatile("s_waitcnt vmcnt(0)" ::: "memory");
        __syncthreads();
        bf16x8 fa[AFR], fb[BFR];
#pragma unroll
        for (int f = 0; f < AFR; f++) {
            int ar = wr * (BM / 2) + f * 16 + lr16;
            fa[f] = *(const bf16x8*)&As[ar * 32 + (lg ^ (ar & 3)) * 8];
        }
#pragma unroll
        for (int f = 0; f < BFR; f++) {
            int br = wc * (BN / 2) + f * 16 + lr16;
            fb[f] = *(const bf16x8*)&Bs[br * 32 + (lg ^ (br & 3)) * 8];
        }
#pragma unroll
        for (int fi = 0; fi < AFR; fi++)
#pragma unroll
            for (int fj = 0; fj < BFR; fj++)
                acc[fi][fj] = __builtin_amdgcn_mfma_f32_16x16x32_bf16(fa[fi], fb[fj], acc[fi][fj], 0, 0, 0);
    }
#pragma unroll
    for (int fi = 0; fi < AFR; fi++)
#pragma unroll
        for (int fj = 0; fj < BFR; fj++)
#pragma unroll
            for (int r = 0; r < 4; r++) {
                int m = bm + wr * (BM / 2) + fi * 16 + lg * 4 + r;
                int n = bn + wc * (BN / 2) + fj * 16 + lr16;
                float v = acc[fi][fj][r];
                if (bias) v += bias[n];
                if (act == 1) v = fmaxf(v, 0.f) + log1pf(expf(-fabsf(v)));
                if (resid) v += resid[(size_t)m * ldr + n];
                C[(size_t)m * ldc + n] = v;
            }
}

// ---------------------------------------------------------------- x_proj split-K (N=64)
__global__ __launch_bounds__(256) void k_gemm_n64_sk(const unsigned short* __restrict__ A, int lda,
                                                     const unsigned short* __restrict__ W, int ldw,
                                                     float* __restrict__ part) {
    __shared__ __align__(16) unsigned short As[128 * 32];
    __shared__ __align__(16) unsigned short Bs[64 * 32];
    const int bm = blockIdx.x * 128;
    const int koff = blockIdx.y * 128;
    const int tid = threadIdx.x;
    const int w = tid >> 6, l = tid & 63;
    const int lg = l >> 4, lr16 = l & 15;
    f32x4 acc[2][4] = {};
    for (int k0 = koff; k0 < koff + 128; k0 += 32) {
        __syncthreads();
#pragma unroll
        for (int i = 0; i < 2; i++) {
            int slot = i * 256 + tid;
            int row = slot >> 2, s = slot & 3;
            int sg = s ^ (row & 3);
            __builtin_amdgcn_global_load_lds(
                (const __attribute__((address_space(1))) unsigned int*)(A + (size_t)(bm + row) * lda + k0 + sg * 8),
                (__attribute__((address_space(3))) unsigned int*)(As + slot * 8), 16, 0, 0);
        }
        {
            int slot = tid;
            int row = slot >> 2, s = slot & 3;
            int sg = s ^ (row & 3);
            __builtin_amdgcn_global_load_lds(
                (const __attribute__((address_space(1))) unsigned int*)(W + (size_t)row * ldw + k0 + sg * 8),
                (__attribute__((address_space(3))) unsigned int*)(Bs + slot * 8), 16, 0, 0);
        }
        asm volatile("s_waitcnt vmcnt(0)" ::: "memory");
        __syncthreads();
        bf16x8 fa[2], fb[4];
#pragma unroll
        for (int f = 0; f < 2; f++) {
            int ar = w * 32 + f * 16 + lr16;
            fa[f] = *(const bf16x8*)&As[ar * 32 + (lg ^ (ar & 3)) * 8];
        }
#pragma unroll
        for (int f = 0; f < 4; f++) {
            int br = f * 16 + lr16;
            fb[f] = *(const bf16x8*)&Bs[br * 32 + (lg ^ (br & 3)) * 8];
        }
#pragma unroll
        for (int fi = 0; fi < 2; fi++)
#pragma unroll
            for (int fj = 0; fj < 4; fj++)
                acc[fi][fj] = __builtin_amdgcn_mfma_f32_16x16x32_bf16(fa[fi], fb[fj], acc[fi][fj], 0, 0, 0);
    }
    float* out = part + (size_t)blockIdx.y * ((size_t)BQ * SQ * 64);
#pragma unroll
    for (int fi = 0; fi < 2; fi++)
#pragma unroll
        for (int fj = 0; fj < 4; fj++)
#pragma unroll
            for (int r = 0; r < 4; r++) {
                int m = bm + w * 32 + fi * 16 + lg * 4 + r;
                int n = fj * 16 + lr16;
                out[(size_t)m * 64 + n] = acc[fi][fj][r];
            }
}

// ---------------------------------------------------------------- xdbl reduce -> f32 + bf16
__global__ __launch_bounds__(256) void k_xdbl_reduce(const float* __restrict__ part,
                                                     float* __restrict__ xdbl,
                                                     unsigned short* __restrict__ xbf) {
    const int n4 = BQ * SQ * 64 / 4;   // 65536
    int i = blockIdx.x * 256 + threadIdx.x;
    if (i >= n4) return;
    float4 s = ((const float4*)part)[i];
#pragma unroll
    for (int ks = 1; ks < 8; ks++) {
        float4 t = ((const float4*)part)[(size_t)ks * n4 + i];
        s.x += t.x; s.y += t.y; s.z += t.z; s.w += t.w;
    }
    ((float4*)xdbl)[i] = s;
    ushort4 o;
    o.x = f2bf(s.x); o.y = f2bf(s.y); o.z = f2bf(s.z); o.w = f2bf(s.w);
    ((ushort4*)xbf)[i] = o;
}

// ---------------------------------------------------------------- causal conv (k=4) + silu
__global__ __launch_bounds__(256) void k_conv_silu(const float* __restrict__ xz,
                                                   const float* __restrict__ cw,
                                                   const float* __restrict__ cb,
                                                   float* __restrict__ u,
                                                   unsigned short* __restrict__ ubf) {
    int b = blockIdx.z;
    int t0 = blockIdx.x * 64;
    int d = blockIdx.y * 256 + threadIdx.x;
    float4 wv = ((const float4*)cw)[d];
    float bias = cb[d];
    const size_t rs = 2 * DI;
    size_t base = (size_t)b * SQ * rs + d;
    float x0 = 0.f, x1 = 0.f, x2 = 0.f;
    if (t0 > 0) {
        x0 = xz[base + (size_t)(t0 - 3) * rs];
        x1 = xz[base + (size_t)(t0 - 2) * rs];
        x2 = xz[base + (size_t)(t0 - 1) * rs];
    }
    for (int t = t0; t < t0 + 64; t++) {
        float x3 = xz[base + (size_t)t * rs];
        float a = bias + wv.x * x0 + wv.y * x1 + wv.z * x2 + wv.w * x3;
        float sig = 1.f / (1.f + __expf(-a));
        float v = a * sig;
        size_t o = (size_t)(b * SQ + t) * DI + d;
        u[o] = v;
        ubf[o] = f2bf(v);
        x0 = x1; x1 = x2; x2 = x3;
    }
}

// ---------------------------------------------------------------- chunked scan, phase 1
// CHUNK=32, 4 states/lane; block 256 = 4q x 64dl; grid = B * NCH * (DI/64) = 2048
__global__ __launch_bounds__(256) void k_scan_p1(const float* __restrict__ xdbl,
                                                 const float* __restrict__ dt,
                                                 const float* __restrict__ u,
                                                 const float* __restrict__ A_log,
                                                 float* __restrict__ hend,
                                                 float* __restrict__ dchunk) {
    int bc = blockIdx.x >> 4;          // b*NCH + c
    int d0 = (blockIdx.x & 15) << 6;
    int b = bc >> 6;                   // NCH == 64
    int c = bc & (NCH - 1);
    int tid = threadIdx.x;
    int q = tid & 3, dl = tid >> 2;
    int d = d0 + dl;
    float4 av = *(const float4*)&A_log[((size_t)d << 4) + 4 * q];
    float a0 = -expf(av.x) * LOG2E, a1 = -expf(av.y) * LOG2E;
    float a2 = -expf(av.z) * LOG2E, a3 = -expf(av.w) * LOG2E;
    float h0 = 0.f, h1 = 0.f, h2 = 0.f, h3 = 0.f, sumdt = 0.f;
    __shared__ __align__(16) float sdt[32][68], su[32][68];
    __shared__ __align__(16) float sB[32][20];
    int tbase = c * CHUNK;
#pragma unroll
    for (int i = 0; i < 2; i++) {
        int e = i * 256 + tid;
        int tt = e >> 4, j4 = e & 15;
        size_t rowm = (size_t)(b * SQ + tbase + tt);
        *(float4*)&sdt[tt][j4 * 4] = *(const float4*)&dt[rowm * DI + d0 + j4 * 4];
        *(float4*)&su[tt][j4 * 4]  = *(const float4*)&u[rowm * DI + d0 + j4 * 4];
    }
    if (tid < 128) {
        int tt = tid >> 2, j4 = tid & 3;
        size_t rowm = (size_t)(b * SQ + tbase + tt);
        *(float4*)&sB[tt][j4 * 4] = *(const float4*)&xdbl[rowm * 64 + DTR + j4 * 4];
    }
    __syncthreads();
#pragma unroll
    for (int tt = 0; tt < 32; tt++) {
        float dtv = sdt[tt][dl], uv = su[tt][dl];
        float dtu = dtv * uv;
        sumdt += dtv;
        float4 Bv = *(const float4*)&sB[tt][4 * q];
        h0 = exp2f(dtv * a0) * h0 + dtu * Bv.x;
        h1 = exp2f(dtv * a1) * h1 + dtu * Bv.y;
        h2 = exp2f(dtv * a2) * h2 + dtu * Bv.z;
        h3 = exp2f(dtv * a3) * h3 + dtu * Bv.w;
    }
    size_t o = ((size_t)bc << 14) + ((size_t)d << 4) + 4 * q;
    *(float4*)&hend[o] = make_float4(h0, h1, h2, h3);
    *(float4*)&dchunk[o] = make_float4(exp2f(a0 * sumdt), exp2f(a1 * sumdt),
                                       exp2f(a2 * sumdt), exp2f(a3 * sumdt));
}

// ---------------------------------------------------------------- chunked scan, phase 2 (64 chunks)
__global__ __launch_bounds__(256) void k_scan_p2(const float* __restrict__ hend,
                                                 const float* __restrict__ dchunk,
                                                 float* __restrict__ hstart) {
    int tid = blockIdx.x * 256 + threadIdx.x;   // 0 .. B*DI*DSTATE-1
    int b = tid >> 14;
    int ds = tid & 16383;
    float h = 0.f;
    for (int c = 0; c < NCH; c++) {
        size_t o = (((size_t)(b * NCH + c)) << 14) + ds;
        hstart[o] = h;
        h = dchunk[o] * h + hend[o];
    }
}

// ---------------------------------------------------------------- chunked scan, phase 3
// CHUNK=32; z gate preloaded in regs per quad; output tt spread across quads
// (xor-butterfly leaves full 16-state sum in ALL lanes, so any quad can write).
__global__ __launch_bounds__(256) void k_scan_p3(const float* __restrict__ xdbl,
                                                 const float* __restrict__ dt,
                                                 const float* __restrict__ u,
                                                 const float* __restrict__ xz,
                                                 const float* __restrict__ A_log,
                                                 const float* __restrict__ Dp,
                                                 const float* __restrict__ hstart,
                                                 unsigned short* __restrict__ yout) {
    int bc = blockIdx.x >> 4;
    int d0 = (blockIdx.x & 15) << 6;
    int b = bc >> 6;                   // NCH == 64
    int c = bc & (NCH - 1);
    int tid = threadIdx.x;
    int q = tid & 3, dl = tid >> 2;
    int d = d0 + dl;
    int tbase = c * CHUNK;
    // preload this quad's 8 gate inputs (tt = q, q+4, ..., q+28)
    float zr[8];
#pragma unroll
    for (int i = 0; i < 8; i++) {
        size_t rowm = (size_t)(b * SQ + tbase + i * 4 + q);
        zr[i] = xz[rowm * (2 * DI) + DI + d];
    }
    float4 av = *(const float4*)&A_log[((size_t)d << 4) + 4 * q];
    float a0 = -expf(av.x) * LOG2E, a1 = -expf(av.y) * LOG2E;
    float a2 = -expf(av.z) * LOG2E, a3 = -expf(av.w) * LOG2E;
    size_t o = ((size_t)bc << 14) + ((size_t)d << 4) + 4 * q;
    float4 hv = *(const float4*)&hstart[o];
    float h0 = hv.x, h1 = hv.y, h2 = hv.z, h3 = hv.w;
    float Dv = Dp[d];
    __shared__ __align__(16) float sdt[32][68], su[32][68];
    __shared__ __align__(16) float sBC[32][36];
#pragma unroll
    for (int i = 0; i < 2; i++) {
        int e = i * 256 + tid;
        int tt = e >> 4, j4 = e & 15;
        size_t rowm = (size_t)(b * SQ + tbase + tt);
        *(float4*)&sdt[tt][j4 * 4] = *(const float4*)&dt[rowm * DI + d0 + j4 * 4];
        *(float4*)&su[tt][j4 * 4]  = *(const float4*)&u[rowm * DI + d0 + j4 * 4];
    }
    {
        int tt = tid >> 3, j4 = tid & 7;
        size_t rowm = (size_t)(b * SQ + tbase + tt);
        *(float4*)&sBC[tt][j4 * 4] = *(const float4*)&xdbl[rowm * 64 + DTR + j4 * 4];
    }
    __syncthreads();
#pragma unroll
    for (int tt = 0; tt < 32; tt++) {
        float dtv = sdt[tt][dl], uv = su[tt][dl];
        float dtu = dtv * uv;
        float4 Bv = *(const float4*)&sBC[tt][4 * q];
        float4 Cv = *(const float4*)&sBC[tt][16 + 4 * q];
        h0 = exp2f(dtv * a0) * h0 + dtu * Bv.x;
        h1 = exp2f(dtv * a1) * h1 + dtu * Bv.y;
        h2 = exp2f(dtv * a2) * h2 + dtu * Bv.z;
        h3 = exp2f(dtv * a3) * h3 + dtu * Bv.w;
        float y = h0 * Cv.x + h1 * Cv.y + h2 * Cv.z + h3 * Cv.w;
        y += __shfl_xor(y, 1);
        y += __shfl_xor(y, 2);
        if (q == (tt & 3)) {   // this quad owns output tt; zr statically indexed
            y += uv * Dv;
            float zv = zr[tt >> 2];
            float g = zv / (1.f + __expf(-zv));
            yout[(size_t)(b * SQ + tbase + tt) * DI + d] = f2bf(y * g);
        }
    }
}

// ---------------------------------------------------------------- emb gather (mask int32)
__global__ __launch_bounds__(256) void k_emb(const float* __restrict__ tokens,
                                             const int* __restrict__ mask,
                                             float* __restrict__ emb) {
    int b = blockIdx.x;
    int cnt = 0;
    for (int i = threadIdx.x; i < SQ; i += 256) cnt += mask[b * SQ + i] ? 1 : 0;
#pragma unroll
    for (int off = 32; off >= 1; off >>= 1) cnt += __shfl_xor(cnt, off);
    __shared__ int wc[4];
    if ((threadIdx.x & 63) == 0) wc[threadIdx.x >> 6] = cnt;
    __syncthreads();
    int total = wc[0] + wc[1] + wc[2] + wc[3];
    int idx = total > 0 ? total - 1 : 0;
    for (int i = threadIdx.x; i < DM; i += 256)
        emb[b * DM + i] = tokens[((size_t)b * SQ + idx) * DM + i];
}

// ---------------------------------------------------------------- host
extern "C" void kernel_launch(void* const* d_in, const int* in_sizes, int n_in,
                              void* d_out, int out_size, void* d_ws, size_t ws_size,
                              hipStream_t stream) {
    const float* input_data   = (const float*)d_in[0];
    const int*   mask         = (const int*)d_in[1];
    const float* in_proj_w    = (const float*)d_in[2];
    const float* conv_w       = (const float*)d_in[3];
    const float* conv_b       = (const float*)d_in[4];
    const float* xproj_w      = (const float*)d_in[5];
    const float* dtproj_w     = (const float*)d_in[6];
    const float* dtproj_b     = (const float*)d_in[7];
    const float* A_log        = (const float*)d_in[8];
    const float* Dp           = (const float*)d_in[9];
    const float* outproj_w    = (const float*)d_in[10];
    const float* norm_w       = (const float*)d_in[11];
    const float* final_norm_w = (const float*)d_in[12];
    float* out = (float*)d_out;

    const size_t M = (size_t)BQ * SQ;                  // 4096
    const size_t CS = (size_t)BQ * NCH * DI * DSTATE;  // 2,097,152
    float* x              = (float*)d_ws;                       // M*DM f32
    unsigned short* xn_bf = (unsigned short*)(x + M * DM);      // M*DM bf16
    float* xz             = (float*)(xn_bf + M * DM);           // M*2DI f32
    float* u              = xz + M * 2 * DI;                    // M*DI f32
    float* xdbl           = u + M * DI;                         // M*64 f32
    float* dtb            = xdbl + M * 64;                      // M*DI f32
    unsigned short* ubf   = (unsigned short*)(dtb + M * DI);    // M*DI bf16
    unsigned short* ybf   = ubf + M * DI;                       // M*DI bf16
    float* hend           = (float*)(ybf + M * DI);             // CS
    float* dchunk         = hend + CS;                          // CS
    float* hstart         = dchunk + CS;                        // CS
    float* xpart          = hstart + CS;                        // 8*M*64 f32
    unsigned short* xdbl_bf = (unsigned short*)(xpart + 8 * M * 64); // M*64 bf16
    unsigned short* wbf_in  = xdbl_bf + M * 64;                 // L*2DI*DM
    unsigned short* wbf_out = wbf_in + (size_t)NLAYERS * 2 * DI * DM;  // L*DM*DI
    unsigned short* wbf_x   = wbf_out + (size_t)NLAYERS * DM * DI;     // L*64*DI
    unsigned short* wbf_dt  = wbf_x + (size_t)NLAYERS * 64 * DI;       // L*DI*DTR

    // fused weight conversion (1 dispatch)
    k_cvt_all<<<(N4_ALL + 255) / 256, 256, 0, stream>>>(
        in_proj_w, outproj_w, xproj_w, dtproj_w, wbf_in, wbf_out, wbf_x, wbf_dt);

    // x = transpose(input_data)
    k_transpose<<<dim3(SQ / 32, DM / 32, BQ), dim3(32, 8), 0, stream>>>(input_data, x);

    for (int l = 0; l < NLAYERS; l++) {
        // xn_bf = bf16(rmsnorm(x))
        k_rmsnorm_bf<<<M, 256, 0, stream>>>(x, norm_w + (size_t)l * DM, xn_bf);
        // xz = xn @ in_proj^T   (M x 2048, K=512)
        k_gemm_bf16_t<128, 128, 4, 4><<<dim3(2 * DI / 128, M / 128), 256, 0, stream>>>(
            xn_bf, DM, wbf_in + (size_t)l * 2 * DI * DM, DM, xz, 2 * DI, DM,
            nullptr, 0, nullptr, 0);
        // u = silu(conv(xz[:, :DI]))
        k_conv_silu<<<dim3(SQ / 64, DI / 256, BQ), 256, 0, stream>>>(
            xz, conv_w + (size_t)l * DI * DCONV, conv_b + (size_t)l * DI, u, ubf);
        // xdbl = u @ xproj^T   (split-K 8 + reduce; emits f32 + bf16)
        k_gemm_n64_sk<<<dim3(M / 128, 8), 256, 0, stream>>>(
            ubf, DI, wbf_x + (size_t)l * 64 * DI, DI, xpart);
        k_xdbl_reduce<<<(BQ * SQ * 64 / 4 + 255) / 256, 256, 0, stream>>>(
            xpart, xdbl, xdbl_bf);
        // dt = softplus(xdbl[:, :32] @ dtproj^T + b)   [bf16 MFMA, K=32]
        k_gemm_bf16_t<64, 128, 2, 4><<<dim3(DI / 128, M / 64), 256, 0, stream>>>(
            xdbl_bf, 64, wbf_dt + (size_t)l * DI * DTR, DTR, dtb, DI, DTR,
            dtproj_b + (size_t)l * DI, 1, nullptr, 0);
        // chunked scan (CHUNK=32, 2048 blocks for p1/p3)
        k_scan_p1<<<BQ * NCH * (DI / 64), 256, 0, stream>>>(
            xdbl, dtb, u, A_log + (size_t)l * DI * DSTATE, hend, dchunk);
        k_scan_p2<<<(BQ * DI * DSTATE) / 256, 256, 0, stream>>>(hend, dchunk, hstart);
        k_scan_p3<<<BQ * NCH * (DI / 64), 256, 0, stream>>>(
            xdbl, dtb, u, xz, A_log + (size_t)l * DI * DSTATE, Dp + (size_t)l * DI,
            hstart, ybf);
        // x = x + ybf @ outproj^T   (M x 512, K=1024)
        k_gemm_bf16_t<64, 128, 2, 4><<<dim3(DM / 128, M / 64), 256, 0, stream>>>(
            ybf, DI, wbf_out + (size_t)l * DM * DI, DI, x, DM, DI,
            nullptr, 0, x, DM);
    }

    // tokens = rmsnorm(x, final_norm_w)
    k_rmsnorm_f32<<<M, 256, 0, stream>>>(x, final_norm_w, out);
    // emb
    k_emb<<<BQ, 256, 0, stream>>>(out, mask, out + M * DM);
}